// Round 1
// baseline (292.578 us; speedup 1.0000x reference)
//
#include <hip/hip_runtime.h>
#include <hip/hip_bf16.h>

typedef __attribute__((ext_vector_type(8))) short bf16x8;
typedef __attribute__((ext_vector_type(4))) float f32x4;
using bf16 = __hip_bfloat16;

#define NTOK 4096
#define EPS_LN 1e-5f

enum { EPI_F32 = 0, EPI_QKV = 1, EPI_RELU_BF16 = 2 };

__device__ inline void gload_lds16(const void* g, void* l) {
  __builtin_amdgcn_global_load_lds(
      (const __attribute__((address_space(1))) char*)g,
      (__attribute__((address_space(3))) char*)l, 16, 0, 0);
}

__device__ inline unsigned short f2bfu(float x) {
  bf16 h = __float2bfloat16(x);
  return __builtin_bit_cast(unsigned short, h);
}
__device__ inline bf16 to_bf16(float v) { return __float2bfloat16(v); }
__device__ inline bf16 to_bf16(bf16 v) { return v; }

// ---------------- prep kernels ----------------

__global__ __launch_bounds__(256) void cvt_bf16_kernel(const float* __restrict__ src,
                                                       bf16* __restrict__ dst, int n4) {
  int i = blockIdx.x * 256 + threadIdx.x;
  if (i >= n4) return;
  float4 v = ((const float4*)src)[i];
  ushort4 o;
  o.x = f2bfu(v.x); o.y = f2bfu(v.y); o.z = f2bfu(v.z); o.w = f2bfu(v.w);
  ((ushort4*)dst)[i] = o;
}

template <typename ST>
__global__ __launch_bounds__(256) void transpose_cvt(const ST* __restrict__ src,
                                                     bf16* __restrict__ dst, int R, int C) {
  // src: [outer][R][C] -> dst: [outer][C][R], outer = blockIdx.z
  __shared__ bf16 tile[32][33];
  int o = blockIdx.z;
  int r0 = blockIdx.y * 32, c0 = blockIdx.x * 32;
  int tx = threadIdx.x & 31, ty = threadIdx.x >> 5;  // ty 0..7
  const ST* s = src + (size_t)o * R * C;
  bf16* d = dst + (size_t)o * R * C;
#pragma unroll
  for (int i = 0; i < 32; i += 8)
    tile[ty + i][tx] = to_bf16(s[(size_t)(r0 + ty + i) * C + (c0 + tx)]);
  __syncthreads();
#pragma unroll
  for (int i = 0; i < 32; i += 8)
    d[(size_t)(c0 + ty + i) * R + (r0 + tx)] = tile[tx][ty + i];
}

__global__ __launch_bounds__(256) void pack_bias_kernel(const float* __restrict__ bq,
                                                        const float* __restrict__ bk,
                                                        const float* __restrict__ bv,
                                                        float* __restrict__ out) {
  int i = blockIdx.x * 256 + threadIdx.x;  // 0..3071
  if (i >= 3072) return;
  out[i] = (i < 1024) ? bq[i] : (i < 2048 ? bk[i - 1024] : bv[i - 2048]);
}

// ---------------- GEMM: C[M,N] = A[M,K](bf16) x Bt[N,K](bf16) ----------------
// 128x128 tile, BK=64, 4 waves (2x2), MFMA 16x16x32, global_load_lds staging.

__global__ __launch_bounds__(256) void gemm_bt(
    const bf16* __restrict__ A, const bf16* __restrict__ Bt,
    int M, int N, int K,
    const float* __restrict__ bias,
    float* __restrict__ Cf, bf16* __restrict__ Cb,
    bf16* __restrict__ Qd, bf16* __restrict__ Kd, bf16* __restrict__ Vd,
    int mode) {
  __shared__ bf16 As[128][64];
  __shared__ bf16 Bs[128][64];
  const int tid = threadIdx.x;
  const int wid = tid >> 6, lane = tid & 63;
  const int bm = blockIdx.y, bn = blockIdx.x;
  const int wr = wid >> 1, wc = wid & 1;
  const bf16* Ab = A + (size_t)bm * 128 * K;
  const bf16* Bb = Bt + (size_t)bn * 128 * K;
  f32x4 acc[4][4] = {};
  const int sr = lane >> 3;        // row within 8-row chunk
  const int sc = (lane & 7) * 8;   // element col within 64
  const int ri = lane & 15;
  const int kg = lane >> 4;

  for (int k0 = 0; k0 < K; k0 += 64) {
#pragma unroll
    for (int c = 0; c < 4; ++c) {
      int chunk = wid * 4 + c;
      gload_lds16(Ab + (size_t)(chunk * 8 + sr) * K + k0 + sc,
                  (char*)&As[0][0] + chunk * 1024);
      gload_lds16(Bb + (size_t)(chunk * 8 + sr) * K + k0 + sc,
                  (char*)&Bs[0][0] + chunk * 1024);
    }
    __syncthreads();
#pragma unroll
    for (int kk = 0; kk < 2; ++kk) {
      const int ko = kk * 32 + kg * 8;
      bf16x8 a[4], b[4];
#pragma unroll
      for (int m = 0; m < 4; ++m) a[m] = *(const bf16x8*)&As[wr * 64 + m * 16 + ri][ko];
#pragma unroll
      for (int n = 0; n < 4; ++n) b[n] = *(const bf16x8*)&Bs[wc * 64 + n * 16 + ri][ko];
#pragma unroll
      for (int m = 0; m < 4; ++m)
#pragma unroll
        for (int n = 0; n < 4; ++n)
          acc[m][n] = __builtin_amdgcn_mfma_f32_16x16x32_bf16(a[m], b[n], acc[m][n], 0, 0, 0);
    }
    __syncthreads();
  }

  // epilogue: C[row][col], col = lane&15 (+16n), row = (lane>>4)*4 + r (+16m)
#pragma unroll
  for (int n = 0; n < 4; ++n) {
    int col = bn * 128 + wc * 64 + n * 16 + ri;
    float bv = bias ? bias[col] : 0.f;
#pragma unroll
    for (int m = 0; m < 4; ++m) {
#pragma unroll
      for (int r = 0; r < 4; ++r) {
        int row = bm * 128 + wr * 64 + m * 16 + kg * 4 + r;
        float v = acc[m][n][r] + bv;
        if (mode == EPI_F32) {
          Cf[(size_t)row * N + col] = v;
        } else if (mode == EPI_RELU_BF16) {
          Cb[(size_t)row * N + col] = __float2bfloat16(v > 0.f ? v : 0.f);
        } else {  // EPI_QKV: N=3072, scatter to [B,H,S,64] bf16
          int which = col >> 10;
          int hh = (col >> 6) & 15;
          int dk = col & 63;
          int b = row >> 10, s = row & 1023;
          bf16* dst = (which == 0) ? Qd : (which == 1) ? Kd : Vd;
          dst[(((size_t)(b * 16 + hh)) * 1024 + s) * 64 + dk] = __float2bfloat16(v);
        }
      }
    }
  }
}

// ---------------- flash attention ----------------
// grid: 64 (b,h) * 16 q-tiles ; block 256 = 4 waves, each wave 16 q-rows.
__global__ __launch_bounds__(256) void attn_kernel(
    const bf16* __restrict__ Qb, const bf16* __restrict__ Kb,
    const bf16* __restrict__ VTb, bf16* __restrict__ Ob) {
  __shared__ bf16 Ks[64][64];
  __shared__ bf16 Vt[64][64];     // [d][key]
  __shared__ bf16 Ps[4][16][64];  // per-wave P transpose buffer
  int bh = blockIdx.x >> 4;
  int qt = blockIdx.x & 15;
  int bb = bh >> 4, hh = bh & 15;
  int tid = threadIdx.x, wid = tid >> 6, lane = tid & 63;
  int ri = lane & 15, kg = lane >> 4;
  int sr = lane >> 3, sc = (lane & 7) * 8;
  const bf16* qp = Qb + (size_t)bh * 1024 * 64;
  const bf16* kp = Kb + (size_t)bh * 1024 * 64;
  const bf16* vp = VTb + (size_t)bh * 64 * 1024;
  int q0 = qt * 64 + wid * 16;

  bf16x8 qf[2];
  qf[0] = *(const bf16x8*)(qp + (size_t)(q0 + ri) * 64 + kg * 8);
  qf[1] = *(const bf16x8*)(qp + (size_t)(q0 + ri) * 64 + 32 + kg * 8);

  f32x4 oacc[4] = {};
  float mrun[4] = {-1e30f, -1e30f, -1e30f, -1e30f};
  float lrun[4] = {0.f, 0.f, 0.f, 0.f};

  for (int t = 0; t < 16; ++t) {
    int k0 = t * 64;
#pragma unroll
    for (int c = 0; c < 2; ++c) {
      int chunk = wid * 2 + c;
      gload_lds16(kp + (size_t)(k0 + chunk * 8 + sr) * 64 + sc, (char*)&Ks[0][0] + chunk * 1024);
      gload_lds16(vp + (size_t)(chunk * 8 + sr) * 1024 + k0 + sc, (char*)&Vt[0][0] + chunk * 1024);
    }
    __syncthreads();

    f32x4 sac[4] = {};
#pragma unroll
    for (int kk = 0; kk < 2; ++kk) {
      int ko = kk * 32 + kg * 8;
#pragma unroll
      for (int n = 0; n < 4; ++n) {
        bf16x8 kf = *(const bf16x8*)&Ks[n * 16 + ri][ko];
        sac[n] = __builtin_amdgcn_mfma_f32_16x16x32_bf16(qf[kk], kf, sac[n], 0, 0, 0);
      }
    }
    // online softmax (rows = kg*4+r, cols = n*16 + lane&15)
#pragma unroll
    for (int r = 0; r < 4; ++r) {
      float s0 = sac[0][r] * 0.125f, s1 = sac[1][r] * 0.125f;
      float s2 = sac[2][r] * 0.125f, s3 = sac[3][r] * 0.125f;
      float mt = fmaxf(fmaxf(s0, s1), fmaxf(s2, s3));
      mt = fmaxf(mt, __shfl_xor(mt, 1));
      mt = fmaxf(mt, __shfl_xor(mt, 2));
      mt = fmaxf(mt, __shfl_xor(mt, 4));
      mt = fmaxf(mt, __shfl_xor(mt, 8));
      float mnew = fmaxf(mrun[r], mt);
      float corr = __expf(mrun[r] - mnew);
      mrun[r] = mnew;
      lrun[r] *= corr;
      oacc[0][r] *= corr; oacc[1][r] *= corr; oacc[2][r] *= corr; oacc[3][r] *= corr;
      float p0 = __expf(s0 - mnew), p1 = __expf(s1 - mnew);
      float p2 = __expf(s2 - mnew), p3 = __expf(s3 - mnew);
      float ps = p0 + p1 + p2 + p3;
      ps += __shfl_xor(ps, 1); ps += __shfl_xor(ps, 2);
      ps += __shfl_xor(ps, 4); ps += __shfl_xor(ps, 8);
      lrun[r] += ps;
      int prow = kg * 4 + r;
      Ps[wid][prow][ri] = __float2bfloat16(p0);
      Ps[wid][prow][16 + ri] = __float2bfloat16(p1);
      Ps[wid][prow][32 + ri] = __float2bfloat16(p2);
      Ps[wid][prow][48 + ri] = __float2bfloat16(p3);
    }
    // PV: O += P[16,64] x Vt
#pragma unroll
    for (int kk = 0; kk < 2; ++kk) {
      int ko = kk * 32 + kg * 8;
      bf16x8 pf = *(const bf16x8*)&Ps[wid][ri][ko];
#pragma unroll
      for (int n = 0; n < 4; ++n) {
        bf16x8 vf = *(const bf16x8*)&Vt[n * 16 + ri][ko];
        oacc[n] = __builtin_amdgcn_mfma_f32_16x16x32_bf16(pf, vf, oacc[n], 0, 0, 0);
      }
    }
    __syncthreads();
  }

#pragma unroll
  for (int r = 0; r < 4; ++r) {
    float inv = 1.f / lrun[r];
    int s = q0 + kg * 4 + r;
    size_t base = ((size_t)(bb * 1024 + s)) * 1024 + hh * 64;
#pragma unroll
    for (int n = 0; n < 4; ++n)
      Ob[base + n * 16 + ri] = __float2bfloat16(oacc[n][r] * inv);
  }
}

// ---------------- fused residual + LayerNorm ----------------
__global__ __launch_bounds__(256) void ln_kernel(
    const float* __restrict__ a, const float* __restrict__ b,
    const float* __restrict__ gamma, const float* __restrict__ beta,
    float* __restrict__ out_f32, bf16* __restrict__ out_bf16) {
  int row = blockIdx.x;
  int tid = threadIdx.x;
  float4 av = ((const float4*)(a + (size_t)row * 1024))[tid];
  float4 bv = ((const float4*)(b + (size_t)row * 1024))[tid];
  float4 z;
  z.x = av.x + bv.x; z.y = av.y + bv.y; z.z = av.z + bv.z; z.w = av.w + bv.w;
  float s = z.x + z.y + z.z + z.w;
  float ss = z.x * z.x + z.y * z.y + z.z * z.z + z.w * z.w;
#pragma unroll
  for (int o = 32; o >= 1; o >>= 1) { s += __shfl_xor(s, o); ss += __shfl_xor(ss, o); }
  __shared__ float red[8];
  int wid = tid >> 6;
  if ((tid & 63) == 0) { red[wid] = s; red[4 + wid] = ss; }
  __syncthreads();
  s = red[0] + red[1] + red[2] + red[3];
  ss = red[4] + red[5] + red[6] + red[7];
  float mean = s * (1.f / 1024.f);
  float var = ss * (1.f / 1024.f) - mean * mean;
  var = var > 0.f ? var : 0.f;
  float inv = 1.f / (sqrtf(var) + EPS_LN);
  float4 g = ((const float4*)gamma)[tid];
  float4 be = ((const float4*)beta)[tid];
  float4 y;
  y.x = (z.x - mean) * inv * g.x + be.x;
  y.y = (z.y - mean) * inv * g.y + be.y;
  y.z = (z.z - mean) * inv * g.z + be.z;
  y.w = (z.w - mean) * inv * g.w + be.w;
  ((float4*)(out_f32 + (size_t)row * 1024))[tid] = y;
  if (out_bf16) {
    ushort4 o;
    o.x = f2bfu(y.x); o.y = f2bfu(y.y); o.z = f2bfu(y.z); o.w = f2bfu(y.w);
    ((ushort4*)(out_bf16 + (size_t)row * 1024))[tid] = o;
  }
}

// ---------------- launch ----------------
extern "C" void kernel_launch(void* const* d_in, const int* in_sizes, int n_in,
                              void* d_out, int out_size, void* d_ws, size_t ws_size,
                              hipStream_t stream) {
  const float* x = (const float*)d_in[0];
  const float* wq = (const float*)d_in[1];
  const float* bq = (const float*)d_in[2];
  const float* wk = (const float*)d_in[3];
  const float* bk = (const float*)d_in[4];
  const float* wv = (const float*)d_in[5];
  const float* bv = (const float*)d_in[6];
  const float* wo_w = (const float*)d_in[7];
  const float* wo_b = (const float*)d_in[8];
  const float* g1 = (const float*)d_in[9];
  const float* b1 = (const float*)d_in[10];
  const float* ff1w = (const float*)d_in[11];
  const float* ff1b = (const float*)d_in[12];
  const float* ff2w = (const float*)d_in[13];
  const float* ff2b = (const float*)d_in[14];
  const float* g2 = (const float*)d_in[15];
  const float* b2 = (const float*)d_in[16];

  char* ws = (char*)d_ws;
  size_t off = 0;
  auto alloc = [&](size_t bytes) {
    char* p = ws + off;
    off += (bytes + 255) & ~(size_t)255;
    return p;
  };
  bf16* xb = (bf16*)alloc((size_t)NTOK * 1024 * 2);      // 8MB
  bf16* wqkvt = (bf16*)alloc((size_t)3072 * 1024 * 2);   // 6MB
  bf16* wot = (bf16*)alloc((size_t)1024 * 1024 * 2);     // 2MB
  bf16* ff1t = (bf16*)alloc((size_t)2048 * 1024 * 2);    // 4MB
  bf16* ff2t = (bf16*)alloc((size_t)1024 * 2048 * 2);    // 4MB
  float* qkvbias = (float*)alloc(3072 * 4);
  bf16* qbuf = (bf16*)alloc((size_t)64 * 1024 * 64 * 2);  // 8MB
  bf16* kbuf = (bf16*)alloc((size_t)64 * 1024 * 64 * 2);  // 8MB (contiguous after qbuf)
  bf16* vbuf = (bf16*)alloc((size_t)64 * 1024 * 64 * 2);  // 8MB
  bf16* vtb = (bf16*)alloc((size_t)64 * 64 * 1024 * 2);   // 8MB
  bf16* attnb = (bf16*)alloc((size_t)NTOK * 1024 * 2);    // 8MB
  float* proj = (float*)alloc((size_t)NTOK * 1024 * 4);   // 16MB
  bf16* hb = (bf16*)alloc((size_t)NTOK * 1024 * 2);       // 8MB
  bf16* ff1o = qbuf;          // reuse q+k region (16MB, dead after attention)
  float* ff2o = proj;         // reuse proj (dead after LN1)
  float* hbuf = (float*)d_out;  // use d_out as f32 h scratch (fully rewritten by LN2)

  // prep
  cvt_bf16_kernel<<<(NTOK * 1024 / 4 + 255) / 256, 256, 0, stream>>>(x, xb, NTOK * 1024 / 4);
  transpose_cvt<float><<<dim3(2, 32, 16), 256, 0, stream>>>(wq, wqkvt, 1024, 64);
  transpose_cvt<float><<<dim3(2, 32, 16), 256, 0, stream>>>(wk, wqkvt + 1024 * 1024, 1024, 64);
  transpose_cvt<float><<<dim3(2, 32, 16), 256, 0, stream>>>(wv, wqkvt + 2 * 1024 * 1024, 1024, 64);
  transpose_cvt<float><<<dim3(32, 32, 1), 256, 0, stream>>>(wo_w, wot, 1024, 1024);
  transpose_cvt<float><<<dim3(64, 32, 1), 256, 0, stream>>>(ff1w, ff1t, 1024, 2048);
  transpose_cvt<float><<<dim3(32, 64, 1), 256, 0, stream>>>(ff2w, ff2t, 2048, 1024);
  pack_bias_kernel<<<12, 256, 0, stream>>>(bq, bk, bv, qkvbias);

  // QKV projection: [4096,1024] x [3072,1024]^T
  gemm_bt<<<dim3(24, 32), 256, 0, stream>>>(xb, wqkvt, 4096, 3072, 1024, qkvbias,
                                            nullptr, nullptr, qbuf, kbuf, vbuf, EPI_QKV);
  // V -> V^T per (b,h)
  transpose_cvt<bf16><<<dim3(2, 32, 64), 256, 0, stream>>>(vbuf, vtb, 1024, 64);
  // attention
  attn_kernel<<<dim3(1024), 256, 0, stream>>>(qbuf, kbuf, vtb, attnb);
  // output projection
  gemm_bt<<<dim3(8, 32), 256, 0, stream>>>(attnb, wot, 4096, 1024, 1024, wo_b,
                                           proj, nullptr, nullptr, nullptr, nullptr, EPI_F32);
  // LN1: h = LN(x + proj)
  ln_kernel<<<4096, 256, 0, stream>>>(x, proj, g1, b1, hbuf, hb);
  // FF1 + ReLU
  gemm_bt<<<dim3(16, 32), 256, 0, stream>>>(hb, ff1t, 4096, 2048, 1024, ff1b,
                                            nullptr, ff1o, nullptr, nullptr, nullptr, EPI_RELU_BF16);
  // FF2
  gemm_bt<<<dim3(8, 32), 256, 0, stream>>>(ff1o, ff2t, 4096, 1024, 2048, ff2b,
                                           ff2o, nullptr, nullptr, nullptr, nullptr, EPI_F32);
  // LN2 -> d_out
  ln_kernel<<<4096, 256, 0, stream>>>(hbuf, ff2o, g2, b2, (float*)d_out, nullptr);
}

// Round 2
// 290.769 us; speedup vs baseline: 1.0062x; 1.0062x over previous
//
#include <hip/hip_runtime.h>
#include <hip/hip_bf16.h>

typedef __attribute__((ext_vector_type(8))) short bf16x8;
typedef __attribute__((ext_vector_type(4))) float f32x4;
using bf16 = __hip_bfloat16;

#define NTOK 4096
#define EPS_LN 1e-5f

enum { EPI_F32 = 0, EPI_QKV = 1, EPI_RELU_BF16 = 2 };

__device__ inline void gload_lds16(const void* g, void* l) {
  __builtin_amdgcn_global_load_lds(
      (const __attribute__((address_space(1))) char*)g,
      (__attribute__((address_space(3))) char*)l, 16, 0, 0);
}

__device__ inline unsigned short f2bfu(float x) {
  bf16 h = __float2bfloat16(x);
  return __builtin_bit_cast(unsigned short, h);
}
__device__ inline bf16 to_bf16(float v) { return __float2bfloat16(v); }
__device__ inline bf16 to_bf16(bf16 v) { return v; }

// ---------------- prep kernels ----------------

__global__ __launch_bounds__(256) void cvt_bf16_kernel(const float* __restrict__ src,
                                                       bf16* __restrict__ dst, int n4) {
  int i = blockIdx.x * 256 + threadIdx.x;
  if (i >= n4) return;
  float4 v = ((const float4*)src)[i];
  ushort4 o;
  o.x = f2bfu(v.x); o.y = f2bfu(v.y); o.z = f2bfu(v.z); o.w = f2bfu(v.w);
  ((ushort4*)dst)[i] = o;
}

template <typename ST>
__global__ __launch_bounds__(256) void transpose_cvt(const ST* __restrict__ src,
                                                     bf16* __restrict__ dst, int R, int C) {
  __shared__ bf16 tile[32][33];
  int o = blockIdx.z;
  int r0 = blockIdx.y * 32, c0 = blockIdx.x * 32;
  int tx = threadIdx.x & 31, ty = threadIdx.x >> 5;
  const ST* s = src + (size_t)o * R * C;
  bf16* d = dst + (size_t)o * R * C;
#pragma unroll
  for (int i = 0; i < 32; i += 8)
    tile[ty + i][tx] = to_bf16(s[(size_t)(r0 + ty + i) * C + (c0 + tx)]);
  __syncthreads();
#pragma unroll
  for (int i = 0; i < 32; i += 8)
    d[(size_t)(c0 + ty + i) * R + (r0 + tx)] = tile[tx][ty + i];
}

__global__ __launch_bounds__(256) void pack_bias_kernel(const float* __restrict__ bq,
                                                        const float* __restrict__ bk,
                                                        const float* __restrict__ bv,
                                                        float* __restrict__ out) {
  int i = blockIdx.x * 256 + threadIdx.x;
  if (i >= 3072) return;
  out[i] = (i < 1024) ? bq[i] : (i < 2048 ? bk[i - 1024] : bv[i - 2048]);
}

// ---------------- GEMM: 256x256 tile, 8-phase pipelined, swizzled LDS ----------
// C[M,N] = A[M,K] x Bt[N,K]^T ; optional in-dispatch split-K (partials to
// Cf + sp*M*N). 512 threads = 8 waves (2m x 4n); per-wave output 128x64.

#define VM4 asm volatile("s_waitcnt vmcnt(4)" ::: "memory")
#define NOVM (void)0

#define STAGE_A(T, H, DD) { \
  const bf16* gb = Ab + (size_t)((H) * 128) * lda + (size_t)(T) * 64; \
  _Pragma("unroll") for (int j = 0; j < 2; ++j) { \
    int blk = j * 8 + w; \
    int r = blk * 8 + (lane >> 3); \
    int cb = ((lane & 7) * 16) ^ ((r & 7) << 4); \
    gload_lds16((const char*)(gb + (size_t)r * lda) + cb, \
                (char*)&sA[DD][(H) * 128][0] + blk * 1024); \
  } }

#define STAGE_B(T, H, DD) { \
  const bf16* gb = Bb + (size_t)((H) * 128) * ldb + (size_t)(T) * 64; \
  _Pragma("unroll") for (int j = 0; j < 2; ++j) { \
    int blk = j * 8 + w; \
    int r = blk * 8 + (lane >> 3); \
    int cb = ((lane & 7) * 16) ^ ((r & 7) << 4); \
    gload_lds16((const char*)(gb + (size_t)r * ldb) + cb, \
                (char*)&sB[DD][(H) * 128][0] + blk * 1024); \
  } }

#define LOAD_A(D, MH) { \
  _Pragma("unroll") for (int i = 0; i < 4; ++i) { \
    int row = wm * 128 + ((MH) * 4 + i) * 16 + ri; \
    int swz = (row & 7) << 4; \
    const char* base = (const char*)&sA[D][0][0] + row * 128; \
    a[i][0] = *(const bf16x8*)(base + ((kg * 16) ^ swz)); \
    a[i][1] = *(const bf16x8*)(base + ((64 + kg * 16) ^ swz)); \
  } }

#define LOAD_B(D, NH, BN_) { \
  _Pragma("unroll") for (int j = 0; j < 2; ++j) { \
    int row = wn * 64 + ((NH) * 2 + j) * 16 + ri; \
    int swz = (row & 7) << 4; \
    const char* base = (const char*)&sB[D][0][0] + row * 128; \
    BN_[j][0] = *(const bf16x8*)(base + ((kg * 16) ^ swz)); \
    BN_[j][1] = *(const bf16x8*)(base + ((64 + kg * 16) ^ swz)); \
  } }

#define PHASE(MH, NH, BN_, LOADS, STAGE, VMS) { \
  LOADS; \
  STAGE; \
  __builtin_amdgcn_s_barrier(); \
  asm volatile("s_waitcnt lgkmcnt(0)" ::: "memory"); \
  __builtin_amdgcn_sched_barrier(0); \
  __builtin_amdgcn_s_setprio(1); \
  _Pragma("unroll") for (int i = 0; i < 4; ++i) \
  _Pragma("unroll") for (int j = 0; j < 2; ++j) \
  _Pragma("unroll") for (int kk = 0; kk < 2; ++kk) \
    acc[(MH) * 4 + i][(NH) * 2 + j] = __builtin_amdgcn_mfma_f32_16x16x32_bf16( \
        a[i][kk], BN_[j][kk], acc[(MH) * 4 + i][(NH) * 2 + j], 0, 0, 0); \
  __builtin_amdgcn_s_setprio(0); \
  VMS; \
  __builtin_amdgcn_s_barrier(); \
}

__global__ __launch_bounds__(512, 2) void gemm256(
    const bf16* __restrict__ A, int lda,
    const bf16* __restrict__ Bt, int ldb,
    int M, int N, int K,  // K = per-split extent
    int nbm, int nbn, int nsplit,
    const float* __restrict__ bias,
    float* __restrict__ Cf, bf16* __restrict__ Cb,
    bf16* __restrict__ Qd, bf16* __restrict__ Kd, bf16* __restrict__ Vd,
    int mode) {
  __shared__ bf16 sA[2][256][64];
  __shared__ bf16 sB[2][256][64];
  const int nwg = nbm * nbn * nsplit;
  const int orig = blockIdx.x;
  const int wgid = (orig % 8) * (nwg / 8) + orig / 8;  // nwg % 8 == 0
  const int sp = wgid / (nbm * nbn);
  const int rem = wgid % (nbm * nbn);
  const int bm = rem / nbn, bn = rem % nbn;
  const int tid = threadIdx.x;
  const int w = tid >> 6, lane = tid & 63;
  const int wm = w >> 2, wn = w & 3;
  const int ri = lane & 15, kg = lane >> 4;
  const bf16* Ab = A + (size_t)bm * 256 * lda + (size_t)sp * K;
  const bf16* Bb = Bt + (size_t)bn * 256 * ldb + (size_t)sp * K;
  const int NT = K / 64;

  f32x4 acc[8][4] = {};
  bf16x8 a[4][2], bA[2][2], bB[2][2];

  // prologue: tile0 (A+B) + tile1 (B)
  STAGE_A(0, 0, 0); STAGE_A(0, 1, 0);
  STAGE_B(0, 0, 0); STAGE_B(0, 1, 0);
  STAGE_B(1, 0, 1); STAGE_B(1, 1, 1);
  VM4;
  __builtin_amdgcn_s_barrier();

  for (int t = 0; t < NT; t += 2) {
    int tc2 = (t + 2 < NT) ? t + 2 : NT - 1;
    int tc3 = (t + 3 < NT) ? t + 3 : NT - 1;
    // tile t (dbuf 0)
    PHASE(0, 0, bA, LOAD_A(0, 0); LOAD_B(0, 0, bA), STAGE_A(t + 1, 0, 1), NOVM)
    PHASE(0, 1, bB, LOAD_B(0, 1, bB),               STAGE_A(t + 1, 1, 1), NOVM)
    PHASE(1, 0, bA, LOAD_A(0, 1),                   STAGE_B(tc2, 0, 0),   NOVM)
    PHASE(1, 1, bB, (void)0,                        STAGE_B(tc2, 1, 0),   VM4)
    // tile t+1 (dbuf 1)
    PHASE(0, 0, bA, LOAD_A(1, 0); LOAD_B(1, 0, bA), STAGE_A(tc2, 0, 0),   NOVM)
    PHASE(0, 1, bB, LOAD_B(1, 1, bB),               STAGE_A(tc2, 1, 0),   NOVM)
    PHASE(1, 0, bA, LOAD_A(1, 1),                   STAGE_B(tc3, 0, 1),   NOVM)
    PHASE(1, 1, bB, (void)0,                        STAGE_B(tc3, 1, 1),   VM4)
  }

  // epilogue: C[row][col], col = n*16 + ri, row = m*16 + kg*4 + r
#pragma unroll
  for (int nf = 0; nf < 4; ++nf) {
    int col = bn * 256 + wn * 64 + nf * 16 + ri;
    float bv = (bias && sp == 0) ? bias[col] : 0.f;
#pragma unroll
    for (int mf = 0; mf < 8; ++mf) {
#pragma unroll
      for (int r = 0; r < 4; ++r) {
        int row = bm * 256 + wm * 128 + mf * 16 + kg * 4 + r;
        float v = acc[mf][nf][r] + bv;
        if (mode == EPI_F32) {
          Cf[(size_t)sp * M * N + (size_t)row * N + col] = v;
        } else if (mode == EPI_RELU_BF16) {
          Cb[(size_t)row * N + col] = __float2bfloat16(v > 0.f ? v : 0.f);
        } else {  // EPI_QKV
          int which = col >> 10;
          int hh = (col >> 6) & 15;
          int dk = col & 63;
          int b = row >> 10, s = row & 1023;
          bf16* dst = (which == 0) ? Qd : (which == 1) ? Kd : Vd;
          dst[(((size_t)(b * 16 + hh)) * 1024 + s) * 64 + dk] = __float2bfloat16(v);
        }
      }
    }
  }
}

// ---------------- flash attention (unchanged) ----------------
__global__ __launch_bounds__(256) void attn_kernel(
    const bf16* __restrict__ Qb, const bf16* __restrict__ Kb,
    const bf16* __restrict__ VTb, bf16* __restrict__ Ob) {
  __shared__ bf16 Ks[64][64];
  __shared__ bf16 Vt[64][64];
  __shared__ bf16 Ps[4][16][64];
  int bh = blockIdx.x >> 4;
  int qt = blockIdx.x & 15;
  int bb = bh >> 4, hh = bh & 15;
  int tid = threadIdx.x, wid = tid >> 6, lane = tid & 63;
  int ri = lane & 15, kg = lane >> 4;
  int sr = lane >> 3, sc = (lane & 7) * 8;
  const bf16* qp = Qb + (size_t)bh * 1024 * 64;
  const bf16* kp = Kb + (size_t)bh * 1024 * 64;
  const bf16* vp = VTb + (size_t)bh * 64 * 1024;
  int q0 = qt * 64 + wid * 16;

  bf16x8 qf[2];
  qf[0] = *(const bf16x8*)(qp + (size_t)(q0 + ri) * 64 + kg * 8);
  qf[1] = *(const bf16x8*)(qp + (size_t)(q0 + ri) * 64 + 32 + kg * 8);

  f32x4 oacc[4] = {};
  float mrun[4] = {-1e30f, -1e30f, -1e30f, -1e30f};
  float lrun[4] = {0.f, 0.f, 0.f, 0.f};

  for (int t = 0; t < 16; ++t) {
    int k0 = t * 64;
#pragma unroll
    for (int c = 0; c < 2; ++c) {
      int chunk = wid * 2 + c;
      gload_lds16(kp + (size_t)(k0 + chunk * 8 + sr) * 64 + sc, (char*)&Ks[0][0] + chunk * 1024);
      gload_lds16(vp + (size_t)(chunk * 8 + sr) * 1024 + k0 + sc, (char*)&Vt[0][0] + chunk * 1024);
    }
    __syncthreads();

    f32x4 sac[4] = {};
#pragma unroll
    for (int kk = 0; kk < 2; ++kk) {
      int ko = kk * 32 + kg * 8;
#pragma unroll
      for (int n = 0; n < 4; ++n) {
        bf16x8 kf = *(const bf16x8*)&Ks[n * 16 + ri][ko];
        sac[n] = __builtin_amdgcn_mfma_f32_16x16x32_bf16(qf[kk], kf, sac[n], 0, 0, 0);
      }
    }
#pragma unroll
    for (int r = 0; r < 4; ++r) {
      float s0 = sac[0][r] * 0.125f, s1 = sac[1][r] * 0.125f;
      float s2 = sac[2][r] * 0.125f, s3 = sac[3][r] * 0.125f;
      float mt = fmaxf(fmaxf(s0, s1), fmaxf(s2, s3));
      mt = fmaxf(mt, __shfl_xor(mt, 1));
      mt = fmaxf(mt, __shfl_xor(mt, 2));
      mt = fmaxf(mt, __shfl_xor(mt, 4));
      mt = fmaxf(mt, __shfl_xor(mt, 8));
      float mnew = fmaxf(mrun[r], mt);
      float corr = __expf(mrun[r] - mnew);
      mrun[r] = mnew;
      lrun[r] *= corr;
      oacc[0][r] *= corr; oacc[1][r] *= corr; oacc[2][r] *= corr; oacc[3][r] *= corr;
      float p0 = __expf(s0 - mnew), p1 = __expf(s1 - mnew);
      float p2 = __expf(s2 - mnew), p3 = __expf(s3 - mnew);
      float ps = p0 + p1 + p2 + p3;
      ps += __shfl_xor(ps, 1); ps += __shfl_xor(ps, 2);
      ps += __shfl_xor(ps, 4); ps += __shfl_xor(ps, 8);
      lrun[r] += ps;
      int prow = kg * 4 + r;
      Ps[wid][prow][ri] = __float2bfloat16(p0);
      Ps[wid][prow][16 + ri] = __float2bfloat16(p1);
      Ps[wid][prow][32 + ri] = __float2bfloat16(p2);
      Ps[wid][prow][48 + ri] = __float2bfloat16(p3);
    }
#pragma unroll
    for (int kk = 0; kk < 2; ++kk) {
      int ko = kk * 32 + kg * 8;
      bf16x8 pf = *(const bf16x8*)&Ps[wid][ri][ko];
#pragma unroll
      for (int n = 0; n < 4; ++n) {
        bf16x8 vf = *(const bf16x8*)&Vt[n * 16 + ri][ko];
        oacc[n] = __builtin_amdgcn_mfma_f32_16x16x32_bf16(pf, vf, oacc[n], 0, 0, 0);
      }
    }
    __syncthreads();
  }

#pragma unroll
  for (int r = 0; r < 4; ++r) {
    float inv = 1.f / lrun[r];
    int s = q0 + kg * 4 + r;
    size_t base = ((size_t)(bb * 1024 + s)) * 1024 + hh * 64;
#pragma unroll
    for (int n = 0; n < 4; ++n)
      Ob[base + n * 16 + ri] = __float2bfloat16(oacc[n][r] * inv);
  }
}

// ---------------- fused residual + LayerNorm (2 or 3 inputs) ----------------
__global__ __launch_bounds__(256) void ln_kernel(
    const float* __restrict__ a, const float* __restrict__ b,
    const float* __restrict__ c,
    const float* __restrict__ gamma, const float* __restrict__ beta,
    float* __restrict__ out_f32, bf16* __restrict__ out_bf16) {
  int row = blockIdx.x;
  int tid = threadIdx.x;
  float4 av = ((const float4*)(a + (size_t)row * 1024))[tid];
  float4 bv = ((const float4*)(b + (size_t)row * 1024))[tid];
  float4 z;
  z.x = av.x + bv.x; z.y = av.y + bv.y; z.z = av.z + bv.z; z.w = av.w + bv.w;
  if (c) {
    float4 cv = ((const float4*)(c + (size_t)row * 1024))[tid];
    z.x += cv.x; z.y += cv.y; z.z += cv.z; z.w += cv.w;
  }
  float s = z.x + z.y + z.z + z.w;
  float ss = z.x * z.x + z.y * z.y + z.z * z.z + z.w * z.w;
#pragma unroll
  for (int o = 32; o >= 1; o >>= 1) { s += __shfl_xor(s, o); ss += __shfl_xor(ss, o); }
  __shared__ float red[8];
  int wid = tid >> 6;
  if ((tid & 63) == 0) { red[wid] = s; red[4 + wid] = ss; }
  __syncthreads();
  s = red[0] + red[1] + red[2] + red[3];
  ss = red[4] + red[5] + red[6] + red[7];
  float mean = s * (1.f / 1024.f);
  float var = ss * (1.f / 1024.f) - mean * mean;
  var = var > 0.f ? var : 0.f;
  float inv = 1.f / (sqrtf(var) + EPS_LN);
  float4 g = ((const float4*)gamma)[tid];
  float4 be = ((const float4*)beta)[tid];
  float4 y;
  y.x = (z.x - mean) * inv * g.x + be.x;
  y.y = (z.y - mean) * inv * g.y + be.y;
  y.z = (z.z - mean) * inv * g.z + be.z;
  y.w = (z.w - mean) * inv * g.w + be.w;
  ((float4*)(out_f32 + (size_t)row * 1024))[tid] = y;
  if (out_bf16) {
    ushort4 o;
    o.x = f2bfu(y.x); o.y = f2bfu(y.y); o.z = f2bfu(y.z); o.w = f2bfu(y.w);
    ((ushort4*)(out_bf16 + (size_t)row * 1024))[tid] = o;
  }
}

// ---------------- launch ----------------
extern "C" void kernel_launch(void* const* d_in, const int* in_sizes, int n_in,
                              void* d_out, int out_size, void* d_ws, size_t ws_size,
                              hipStream_t stream) {
  const float* x = (const float*)d_in[0];
  const float* wq = (const float*)d_in[1];
  const float* bq = (const float*)d_in[2];
  const float* wk = (const float*)d_in[3];
  const float* bk = (const float*)d_in[4];
  const float* wv = (const float*)d_in[5];
  const float* bv = (const float*)d_in[6];
  const float* wo_w = (const float*)d_in[7];
  const float* wo_b = (const float*)d_in[8];
  const float* g1 = (const float*)d_in[9];
  const float* b1 = (const float*)d_in[10];
  const float* ff1w = (const float*)d_in[11];
  const float* ff1b = (const float*)d_in[12];
  const float* ff2w = (const float*)d_in[13];
  const float* ff2b = (const float*)d_in[14];
  const float* g2 = (const float*)d_in[15];
  const float* b2 = (const float*)d_in[16];

  char* ws = (char*)d_ws;
  size_t off = 0;
  auto alloc = [&](size_t bytes) {
    char* p = ws + off;
    off += (bytes + 255) & ~(size_t)255;
    return p;
  };
  bf16* xb = (bf16*)alloc((size_t)NTOK * 1024 * 2);
  bf16* wqkvt = (bf16*)alloc((size_t)3072 * 1024 * 2);
  bf16* wot = (bf16*)alloc((size_t)1024 * 1024 * 2);
  bf16* ff1t = (bf16*)alloc((size_t)2048 * 1024 * 2);
  bf16* ff2t = (bf16*)alloc((size_t)1024 * 2048 * 2);
  float* qkvbias = (float*)alloc(3072 * 4);
  bf16* qbuf = (bf16*)alloc((size_t)64 * 1024 * 64 * 2);
  bf16* kbuf = (bf16*)alloc((size_t)64 * 1024 * 64 * 2);
  bf16* vbuf = (bf16*)alloc((size_t)64 * 1024 * 64 * 2);
  bf16* vtb = (bf16*)alloc((size_t)64 * 64 * 1024 * 2);
  bf16* attnb = (bf16*)alloc((size_t)NTOK * 1024 * 2);
  float* proj = (float*)alloc((size_t)2 * NTOK * 1024 * 4);  // 32MB: 2 split-K partials
  bf16* hb = (bf16*)alloc((size_t)NTOK * 1024 * 2);
  bf16* ff1o = qbuf;            // reuse q+k region (16MB, dead after attention)
  float* hbuf = (float*)d_out;  // f32 h scratch (fully rewritten by LN2)

  // prep
  cvt_bf16_kernel<<<(NTOK * 1024 / 4 + 255) / 256, 256, 0, stream>>>(x, xb, NTOK * 1024 / 4);
  transpose_cvt<float><<<dim3(2, 32, 16), 256, 0, stream>>>(wq, wqkvt, 1024, 64);
  transpose_cvt<float><<<dim3(2, 32, 16), 256, 0, stream>>>(wk, wqkvt + 1024 * 1024, 1024, 64);
  transpose_cvt<float><<<dim3(2, 32, 16), 256, 0, stream>>>(wv, wqkvt + 2 * 1024 * 1024, 1024, 64);
  transpose_cvt<float><<<dim3(32, 32, 1), 256, 0, stream>>>(wo_w, wot, 1024, 1024);
  transpose_cvt<float><<<dim3(64, 32, 1), 256, 0, stream>>>(ff1w, ff1t, 1024, 2048);
  transpose_cvt<float><<<dim3(32, 64, 1), 256, 0, stream>>>(ff2w, ff2t, 2048, 1024);
  pack_bias_kernel<<<12, 256, 0, stream>>>(bq, bk, bv, qkvbias);

  // QKV: [4096,1024] x [3072,1024]^T, 192 blocks
  gemm256<<<192, 512, 0, stream>>>(xb, 1024, wqkvt, 1024, 4096, 3072, 1024,
                                   16, 12, 1, qkvbias,
                                   nullptr, nullptr, qbuf, kbuf, vbuf, EPI_QKV);
  // V -> V^T per (b,h)
  transpose_cvt<bf16><<<dim3(2, 32, 64), 256, 0, stream>>>(vbuf, vtb, 1024, 64);
  // attention
  attn_kernel<<<dim3(1024), 256, 0, stream>>>(qbuf, kbuf, vtb, attnb);
  // output projection, split-K=2 (partials) -> proj[0], proj[1]
  gemm256<<<128, 512, 0, stream>>>(attnb, 1024, wot, 1024, 4096, 1024, 512,
                                   16, 4, 2, wo_b,
                                   proj, nullptr, nullptr, nullptr, nullptr, EPI_F32);
  // LN1: h = LN(x + projA + projB)
  ln_kernel<<<4096, 256, 0, stream>>>(x, proj, proj + (size_t)NTOK * 1024,
                                      g1, b1, hbuf, hb);
  // FF1 + ReLU: [4096,1024] x [2048,1024]^T, 128 blocks
  gemm256<<<128, 512, 0, stream>>>(hb, 1024, ff1t, 1024, 4096, 2048, 1024,
                                   16, 8, 1, ff1b,
                                   nullptr, ff1o, nullptr, nullptr, nullptr, EPI_RELU_BF16);
  // FF2: [4096,2048] x [1024,2048]^T, split-K=2 -> proj partials (reused)
  gemm256<<<128, 512, 0, stream>>>(ff1o, 2048, ff2t, 2048, 4096, 1024, 1024,
                                   16, 4, 2, ff2b,
                                   proj, nullptr, nullptr, nullptr, nullptr, EPI_F32);
  // LN2 -> d_out
  ln_kernel<<<4096, 256, 0, stream>>>(hbuf, proj, proj + (size_t)NTOK * 1024,
                                      g2, b2, (float*)d_out, nullptr);
}

// Round 3
// 275.981 us; speedup vs baseline: 1.0601x; 1.0536x over previous
//
#include <hip/hip_runtime.h>
#include <hip/hip_bf16.h>

typedef __attribute__((ext_vector_type(8))) short bf16x8;
typedef __attribute__((ext_vector_type(4))) float f32x4;
using bf16 = __hip_bfloat16;

#define NTOK 4096
#define EPS_LN 1e-5f

enum { EPI_F32 = 0, EPI_QKV = 1, EPI_RELU_BF16 = 2 };

__device__ inline void gload_lds16(const void* g, void* l) {
  __builtin_amdgcn_global_load_lds(
      (const __attribute__((address_space(1))) char*)g,
      (__attribute__((address_space(3))) char*)l, 16, 0, 0);
}

__device__ inline unsigned ldsoff(const void* p) {
  return (unsigned)(size_t)(const __attribute__((address_space(3))) char*)p;
}

__device__ inline unsigned short f2bfu(float x) {
  bf16 h = __float2bfloat16(x);
  return __builtin_bit_cast(unsigned short, h);
}
__device__ inline bf16 to_bf16(float v) { return __float2bfloat16(v); }
__device__ inline bf16 to_bf16(bf16 v) { return v; }

// ---------------- prep kernels ----------------

__global__ __launch_bounds__(256) void cvt_bf16_kernel(const float* __restrict__ src,
                                                       bf16* __restrict__ dst, int n4) {
  int i = blockIdx.x * 256 + threadIdx.x;
  if (i >= n4) return;
  float4 v = ((const float4*)src)[i];
  ushort4 o;
  o.x = f2bfu(v.x); o.y = f2bfu(v.y); o.z = f2bfu(v.z); o.w = f2bfu(v.w);
  ((ushort4*)dst)[i] = o;
}

template <typename ST>
__global__ __launch_bounds__(256) void transpose_cvt(const ST* __restrict__ src,
                                                     bf16* __restrict__ dst, int R, int C) {
  __shared__ bf16 tile[32][33];
  int o = blockIdx.z;
  int r0 = blockIdx.y * 32, c0 = blockIdx.x * 32;
  int tx = threadIdx.x & 31, ty = threadIdx.x >> 5;
  const ST* s = src + (size_t)o * R * C;
  bf16* d = dst + (size_t)o * R * C;
#pragma unroll
  for (int i = 0; i < 32; i += 8)
    tile[ty + i][tx] = to_bf16(s[(size_t)(r0 + ty + i) * C + (c0 + tx)]);
  __syncthreads();
#pragma unroll
  for (int i = 0; i < 32; i += 8)
    d[(size_t)(c0 + ty + i) * R + (r0 + tx)] = tile[tx][ty + i];
}

__global__ __launch_bounds__(256) void pack_bias_kernel(const float* __restrict__ bq,
                                                        const float* __restrict__ bk,
                                                        const float* __restrict__ bv,
                                                        float* __restrict__ out) {
  int i = blockIdx.x * 256 + threadIdx.x;
  if (i >= 3072) return;
  out[i] = (i < 1024) ? bq[i] : (i < 2048 ? bk[i - 1024] : bv[i - 2048]);
}

// ---------------- GEMM: 256x256 tile, 8-phase pipelined, swizzled LDS ----------
// C[M,N] = A[M,K] x Bt[N,K]^T ; optional split-K partials. 512 thr = 8 waves.

#define VM4 asm volatile("s_waitcnt vmcnt(4)" ::: "memory")
#define VM0 asm volatile("s_waitcnt vmcnt(0)" ::: "memory")
#define NOVM
#define DSR(dst, ad) asm volatile("ds_read_b128 %0, %1" : "=v"(dst) : "v"(ad))

#define LA(D, MH) { _Pragma("unroll") for (int i = 0; i < 4; ++i) { \
    DSR(a[i][0], adA[i][0] + ((D) * 32768u + (MH) * 8192u)); \
    DSR(a[i][1], adA[i][1] + ((D) * 32768u + (MH) * 8192u)); } }

#define LB(D, NH, BN_) { _Pragma("unroll") for (int j = 0; j < 2; ++j) { \
    DSR(BN_[j][0], adB[j][0] + ((D) * 32768u + (NH) * 4096u)); \
    DSR(BN_[j][1], adB[j][1] + ((D) * 32768u + (NH) * 4096u)); } }

#define SA(C, H, DD) { _Pragma("unroll") for (int q = 0; q < 2; ++q) \
    gload_lds16(gA[q][H] + (C), sAbase + (DD) * 32768 + (H) * 16384 + (q * 8 + w) * 1024); }
#define SB(C, H, DD) { _Pragma("unroll") for (int q = 0; q < 2; ++q) \
    gload_lds16(gB[q][H] + (C), sBbase + (DD) * 32768 + (H) * 16384 + (q * 8 + w) * 1024); }

#define PHASE(MH, NH, BN_, LOADS, STAGE, VMS) { \
  LOADS; \
  STAGE; \
  __builtin_amdgcn_s_barrier(); \
  asm volatile("s_waitcnt lgkmcnt(0)" ::: "memory"); \
  __builtin_amdgcn_sched_barrier(0); \
  __builtin_amdgcn_s_setprio(1); \
  _Pragma("unroll") for (int i = 0; i < 4; ++i) \
  _Pragma("unroll") for (int j = 0; j < 2; ++j) \
  _Pragma("unroll") for (int kk = 0; kk < 2; ++kk) \
    acc[(MH) * 4 + i][(NH) * 2 + j] = __builtin_amdgcn_mfma_f32_16x16x32_bf16( \
        a[i][kk], BN_[j][kk], acc[(MH) * 4 + i][(NH) * 2 + j], 0, 0, 0); \
  __builtin_amdgcn_s_setprio(0); \
  VMS; \
  __builtin_amdgcn_s_barrier(); \
}

__global__ __launch_bounds__(512, 2) void gemm256(
    const bf16* __restrict__ A, int lda,
    const bf16* __restrict__ Bt, int ldb,
    int M, int N, int K,  // K = per-split extent
    int nbm, int nbn, int nsplit,
    const float* __restrict__ bias,
    float* __restrict__ Cf, bf16* __restrict__ Cb,
    bf16* __restrict__ Qd, bf16* __restrict__ Kd, bf16* __restrict__ Vd,
    int mode) {
  __shared__ bf16 sA[2][256][64];
  __shared__ bf16 sB[2][256][64];
  const int nwg = nbm * nbn * nsplit;
  const int orig = blockIdx.x;
  const int wgid = (orig % 8) * (nwg / 8) + orig / 8;  // nwg % 8 == 0
  const int sp = wgid / (nbm * nbn);
  const int rem = wgid % (nbm * nbn);
  const int bm = rem / nbn, bn = rem % nbn;
  const int tid = threadIdx.x;
  const int w = tid >> 6, lane = tid & 63;
  const int wm = w >> 2, wn = w & 3;
  const int ri = lane & 15, kg = lane >> 4;
  const bf16* Ab = A + (size_t)bm * 256 * lda + (size_t)sp * K;
  const bf16* Bb = Bt + (size_t)bn * 256 * ldb + (size_t)sp * K;
  const int NT = K / 64;
  char* sAbase = (char*)&sA[0][0][0];
  char* sBbase = (char*)&sB[0][0][0];

  // loop-invariant LDS read addresses (dbuf0, MH=0 / NH=0 bases)
  unsigned adA[4][2], adB[2][2];
  const unsigned sA0 = ldsoff(sAbase), sB0 = ldsoff(sBbase);
#pragma unroll
  for (int i = 0; i < 4; ++i) {
    int row = wm * 128 + i * 16 + ri;
    unsigned swz = (unsigned)((row & 7) << 4);
    adA[i][0] = sA0 + row * 128 + ((kg * 16) ^ swz);
    adA[i][1] = sA0 + row * 128 + ((64 + kg * 16) ^ swz);
  }
#pragma unroll
  for (int j = 0; j < 2; ++j) {
    int row = wn * 64 + j * 16 + ri;
    unsigned swz = (unsigned)((row & 7) << 4);
    adB[j][0] = sB0 + row * 128 + ((kg * 16) ^ swz);
    adB[j][1] = sB0 + row * 128 + ((64 + kg * 16) ^ swz);
  }

  // loop-invariant global stage pointers (tile 0 base), +256B per iteration
  const char* gA[2][2];
  const char* gB[2][2];
#pragma unroll
  for (int q = 0; q < 2; ++q)
#pragma unroll
    for (int h = 0; h < 2; ++h) {
      int r = h * 128 + (q * 8 + w) * 8 + (lane >> 3);
      int cb = ((lane & 7) * 16) ^ ((r & 7) << 4);
      gA[q][h] = (const char*)(Ab + (size_t)r * lda) + cb;
      gB[q][h] = (const char*)(Bb + (size_t)r * ldb) + cb;
    }

  f32x4 acc[8][4] = {};
  bf16x8 a[4][2], bA[2][2], bB[2][2];

  // prologue: tile0 A+B, tile1 B
  SA(0, 0, 0) SA(0, 1, 0) SB(0, 0, 0) SB(0, 1, 0) SB(128, 0, 1) SB(128, 1, 1)
  VM4;
  __builtin_amdgcn_s_barrier();

  const int niter = (NT - 2) / 2;
  for (int it = 0; it < niter; ++it) {
    // tile t (dbuf 0)
    PHASE(0, 0, bA, LA(0, 0); LB(0, 0, bA), SA(128, 0, 1), NOVM)
    PHASE(0, 1, bB, LB(0, 1, bB),           SA(128, 1, 1), NOVM)
    PHASE(1, 0, bA, LA(0, 1),               SB(256, 0, 0), NOVM)
    PHASE(1, 1, bB, ,                       SB(256, 1, 0), VM4)
    // tile t+1 (dbuf 1)
    PHASE(0, 0, bA, LA(1, 0); LB(1, 0, bA), SA(256, 0, 0), NOVM)
    PHASE(0, 1, bB, LB(1, 1, bB),           SA(256, 1, 0), NOVM)
    PHASE(1, 0, bA, LA(1, 1),               SB(384, 0, 1), NOVM)
    PHASE(1, 1, bB, ,                       SB(384, 1, 1), VM4)
#pragma unroll
    for (int q = 0; q < 2; ++q)
#pragma unroll
      for (int h = 0; h < 2; ++h) { gA[q][h] += 256; gB[q][h] += 256; }
  }
  // tail: tiles NT-2 (dbuf0), NT-1 (dbuf1); stage only A(NT-1)
  PHASE(0, 0, bA, LA(0, 0); LB(0, 0, bA), SA(128, 0, 1), NOVM)
  PHASE(0, 1, bB, LB(0, 1, bB),           SA(128, 1, 1), NOVM)
  PHASE(1, 0, bA, LA(0, 1),               ,              NOVM)
  PHASE(1, 1, bB, ,                       ,              VM0)
  PHASE(0, 0, bA, LA(1, 0); LB(1, 0, bA), ,              NOVM)
  PHASE(0, 1, bB, LB(1, 1, bB),           ,              NOVM)
  PHASE(1, 0, bA, LA(1, 1),               ,              NOVM)
  PHASE(1, 1, bB, ,                       ,              NOVM)

  // epilogue: C[row][col], col = n*16 + ri, row = m*16 + kg*4 + r
#pragma unroll
  for (int nf = 0; nf < 4; ++nf) {
    int col = bn * 256 + wn * 64 + nf * 16 + ri;
    float bv = (bias && sp == 0) ? bias[col] : 0.f;
#pragma unroll
    for (int mf = 0; mf < 8; ++mf) {
#pragma unroll
      for (int r = 0; r < 4; ++r) {
        int row = bm * 256 + wm * 128 + mf * 16 + kg * 4 + r;
        float v = acc[mf][nf][r] + bv;
        if (mode == EPI_F32) {
          Cf[(size_t)sp * M * N + (size_t)row * N + col] = v;
        } else if (mode == EPI_RELU_BF16) {
          Cb[(size_t)row * N + col] = __float2bfloat16(v > 0.f ? v : 0.f);
        } else {  // EPI_QKV
          int which = col >> 10;
          int hh = (col >> 6) & 15;
          int dk = col & 63;
          int b = row >> 10, s = row & 1023;
          bf16* dst = (which == 0) ? Qd : (which == 1) ? Kd : Vd;
          dst[(((size_t)(b * 16 + hh)) * 1024 + s) * 64 + dk] = __float2bfloat16(v);
        }
      }
    }
  }
}

// ---------------- flash attention (unchanged) ----------------
__global__ __launch_bounds__(256) void attn_kernel(
    const bf16* __restrict__ Qb, const bf16* __restrict__ Kb,
    const bf16* __restrict__ VTb, bf16* __restrict__ Ob) {
  __shared__ bf16 Ks[64][64];
  __shared__ bf16 Vt[64][64];
  __shared__ bf16 Ps[4][16][64];
  int bh = blockIdx.x >> 4;
  int qt = blockIdx.x & 15;
  int bb = bh >> 4, hh = bh & 15;
  int tid = threadIdx.x, wid = tid >> 6, lane = tid & 63;
  int ri = lane & 15, kg = lane >> 4;
  int sr = lane >> 3, sc = (lane & 7) * 8;
  const bf16* qp = Qb + (size_t)bh * 1024 * 64;
  const bf16* kp = Kb + (size_t)bh * 1024 * 64;
  const bf16* vp = VTb + (size_t)bh * 64 * 1024;
  int q0 = qt * 64 + wid * 16;

  bf16x8 qf[2];
  qf[0] = *(const bf16x8*)(qp + (size_t)(q0 + ri) * 64 + kg * 8);
  qf[1] = *(const bf16x8*)(qp + (size_t)(q0 + ri) * 64 + 32 + kg * 8);

  f32x4 oacc[4] = {};
  float mrun[4] = {-1e30f, -1e30f, -1e30f, -1e30f};
  float lrun[4] = {0.f, 0.f, 0.f, 0.f};

  for (int t = 0; t < 16; ++t) {
    int k0 = t * 64;
#pragma unroll
    for (int c = 0; c < 2; ++c) {
      int chunk = wid * 2 + c;
      gload_lds16(kp + (size_t)(k0 + chunk * 8 + sr) * 64 + sc, (char*)&Ks[0][0] + chunk * 1024);
      gload_lds16(vp + (size_t)(chunk * 8 + sr) * 1024 + k0 + sc, (char*)&Vt[0][0] + chunk * 1024);
    }
    __syncthreads();

    f32x4 sac[4] = {};
#pragma unroll
    for (int kk = 0; kk < 2; ++kk) {
      int ko = kk * 32 + kg * 8;
#pragma unroll
      for (int n = 0; n < 4; ++n) {
        bf16x8 kf = *(const bf16x8*)&Ks[n * 16 + ri][ko];
        sac[n] = __builtin_amdgcn_mfma_f32_16x16x32_bf16(qf[kk], kf, sac[n], 0, 0, 0);
      }
    }
#pragma unroll
    for (int r = 0; r < 4; ++r) {
      float s0 = sac[0][r] * 0.125f, s1 = sac[1][r] * 0.125f;
      float s2 = sac[2][r] * 0.125f, s3 = sac[3][r] * 0.125f;
      float mt = fmaxf(fmaxf(s0, s1), fmaxf(s2, s3));
      mt = fmaxf(mt, __shfl_xor(mt, 1));
      mt = fmaxf(mt, __shfl_xor(mt, 2));
      mt = fmaxf(mt, __shfl_xor(mt, 4));
      mt = fmaxf(mt, __shfl_xor(mt, 8));
      float mnew = fmaxf(mrun[r], mt);
      float corr = __expf(mrun[r] - mnew);
      mrun[r] = mnew;
      lrun[r] *= corr;
      oacc[0][r] *= corr; oacc[1][r] *= corr; oacc[2][r] *= corr; oacc[3][r] *= corr;
      float p0 = __expf(s0 - mnew), p1 = __expf(s1 - mnew);
      float p2 = __expf(s2 - mnew), p3 = __expf(s3 - mnew);
      float ps = p0 + p1 + p2 + p3;
      ps += __shfl_xor(ps, 1); ps += __shfl_xor(ps, 2);
      ps += __shfl_xor(ps, 4); ps += __shfl_xor(ps, 8);
      lrun[r] += ps;
      int prow = kg * 4 + r;
      Ps[wid][prow][ri] = __float2bfloat16(p0);
      Ps[wid][prow][16 + ri] = __float2bfloat16(p1);
      Ps[wid][prow][32 + ri] = __float2bfloat16(p2);
      Ps[wid][prow][48 + ri] = __float2bfloat16(p3);
    }
#pragma unroll
    for (int kk = 0; kk < 2; ++kk) {
      int ko = kk * 32 + kg * 8;
      bf16x8 pf = *(const bf16x8*)&Ps[wid][ri][ko];
#pragma unroll
      for (int n = 0; n < 4; ++n) {
        bf16x8 vf = *(const bf16x8*)&Vt[n * 16 + ri][ko];
        oacc[n] = __builtin_amdgcn_mfma_f32_16x16x32_bf16(pf, vf, oacc[n], 0, 0, 0);
      }
    }
    __syncthreads();
  }

#pragma unroll
  for (int r = 0; r < 4; ++r) {
    float inv = 1.f / lrun[r];
    int s = q0 + kg * 4 + r;
    size_t base = ((size_t)(bb * 1024 + s)) * 1024 + hh * 64;
#pragma unroll
    for (int n = 0; n < 4; ++n)
      Ob[base + n * 16 + ri] = __float2bfloat16(oacc[n][r] * inv);
  }
}

// ---------------- fused residual + LayerNorm (2 or 3 inputs) ----------------
__global__ __launch_bounds__(256) void ln_kernel(
    const float* __restrict__ a, const float* __restrict__ b,
    const float* __restrict__ c,
    const float* __restrict__ gamma, const float* __restrict__ beta,
    float* __restrict__ out_f32, bf16* __restrict__ out_bf16) {
  int row = blockIdx.x;
  int tid = threadIdx.x;
  float4 av = ((const float4*)(a + (size_t)row * 1024))[tid];
  float4 bv = ((const float4*)(b + (size_t)row * 1024))[tid];
  float4 z;
  z.x = av.x + bv.x; z.y = av.y + bv.y; z.z = av.z + bv.z; z.w = av.w + bv.w;
  if (c) {
    float4 cv = ((const float4*)(c + (size_t)row * 1024))[tid];
    z.x += cv.x; z.y += cv.y; z.z += cv.z; z.w += cv.w;
  }
  float s = z.x + z.y + z.z + z.w;
  float ss = z.x * z.x + z.y * z.y + z.z * z.z + z.w * z.w;
#pragma unroll
  for (int o = 32; o >= 1; o >>= 1) { s += __shfl_xor(s, o); ss += __shfl_xor(ss, o); }
  __shared__ float red[8];
  int wid = tid >> 6;
  if ((tid & 63) == 0) { red[wid] = s; red[4 + wid] = ss; }
  __syncthreads();
  s = red[0] + red[1] + red[2] + red[3];
  ss = red[4] + red[5] + red[6] + red[7];
  float mean = s * (1.f / 1024.f);
  float var = ss * (1.f / 1024.f) - mean * mean;
  var = var > 0.f ? var : 0.f;
  float inv = 1.f / (sqrtf(var) + EPS_LN);
  float4 g = ((const float4*)gamma)[tid];
  float4 be = ((const float4*)beta)[tid];
  float4 y;
  y.x = (z.x - mean) * inv * g.x + be.x;
  y.y = (z.y - mean) * inv * g.y + be.y;
  y.z = (z.z - mean) * inv * g.z + be.z;
  y.w = (z.w - mean) * inv * g.w + be.w;
  ((float4*)(out_f32 + (size_t)row * 1024))[tid] = y;
  if (out_bf16) {
    ushort4 o;
    o.x = f2bfu(y.x); o.y = f2bfu(y.y); o.z = f2bfu(y.z); o.w = f2bfu(y.w);
    ((ushort4*)(out_bf16 + (size_t)row * 1024))[tid] = o;
  }
}

// ---------------- launch ----------------
extern "C" void kernel_launch(void* const* d_in, const int* in_sizes, int n_in,
                              void* d_out, int out_size, void* d_ws, size_t ws_size,
                              hipStream_t stream) {
  const float* x = (const float*)d_in[0];
  const float* wq = (const float*)d_in[1];
  const float* bq = (const float*)d_in[2];
  const float* wk = (const float*)d_in[3];
  const float* bk = (const float*)d_in[4];
  const float* wv = (const float*)d_in[5];
  const float* bv = (const float*)d_in[6];
  const float* wo_w = (const float*)d_in[7];
  const float* wo_b = (const float*)d_in[8];
  const float* g1 = (const float*)d_in[9];
  const float* b1 = (const float*)d_in[10];
  const float* ff1w = (const float*)d_in[11];
  const float* ff1b = (const float*)d_in[12];
  const float* ff2w = (const float*)d_in[13];
  const float* ff2b = (const float*)d_in[14];
  const float* g2 = (const float*)d_in[15];
  const float* b2 = (const float*)d_in[16];

  char* ws = (char*)d_ws;
  size_t off = 0;
  auto alloc = [&](size_t bytes) {
    char* p = ws + off;
    off += (bytes + 255) & ~(size_t)255;
    return p;
  };
  bf16* xb = (bf16*)alloc((size_t)NTOK * 1024 * 2);
  bf16* wqkvt = (bf16*)alloc((size_t)3072 * 1024 * 2);
  bf16* wot = (bf16*)alloc((size_t)1024 * 1024 * 2);
  bf16* ff1t = (bf16*)alloc((size_t)2048 * 1024 * 2);
  bf16* ff2t = (bf16*)alloc((size_t)1024 * 2048 * 2);
  float* qkvbias = (float*)alloc(3072 * 4);
  bf16* qbuf = (bf16*)alloc((size_t)64 * 1024 * 64 * 2);
  bf16* kbuf = (bf16*)alloc((size_t)64 * 1024 * 64 * 2);
  bf16* vbuf = (bf16*)alloc((size_t)64 * 1024 * 64 * 2);
  bf16* vtb = (bf16*)alloc((size_t)64 * 64 * 1024 * 2);
  bf16* attnb = (bf16*)alloc((size_t)NTOK * 1024 * 2);
  float* proj = (float*)alloc((size_t)2 * NTOK * 1024 * 4);  // 2 split-K partials
  bf16* hb = (bf16*)alloc((size_t)NTOK * 1024 * 2);
  bf16* ff1o = qbuf;            // reuse q+k region (dead after attention)
  float* hbuf = (float*)d_out;  // f32 h scratch (fully rewritten by LN2)

  // prep
  cvt_bf16_kernel<<<(NTOK * 1024 / 4 + 255) / 256, 256, 0, stream>>>(x, xb, NTOK * 1024 / 4);
  transpose_cvt<float><<<dim3(2, 32, 16), 256, 0, stream>>>(wq, wqkvt, 1024, 64);
  transpose_cvt<float><<<dim3(2, 32, 16), 256, 0, stream>>>(wk, wqkvt + 1024 * 1024, 1024, 64);
  transpose_cvt<float><<<dim3(2, 32, 16), 256, 0, stream>>>(wv, wqkvt + 2 * 1024 * 1024, 1024, 64);
  transpose_cvt<float><<<dim3(32, 32, 1), 256, 0, stream>>>(wo_w, wot, 1024, 1024);
  transpose_cvt<float><<<dim3(64, 32, 1), 256, 0, stream>>>(ff1w, ff1t, 1024, 2048);
  transpose_cvt<float><<<dim3(32, 64, 1), 256, 0, stream>>>(ff2w, ff2t, 2048, 1024);
  pack_bias_kernel<<<12, 256, 0, stream>>>(bq, bk, bv, qkvbias);

  // QKV: [4096,1024] x [3072,1024]^T, 192 blocks
  gemm256<<<192, 512, 0, stream>>>(xb, 1024, wqkvt, 1024, 4096, 3072, 1024,
                                   16, 12, 1, qkvbias,
                                   nullptr, nullptr, qbuf, kbuf, vbuf, EPI_QKV);
  // V -> V^T per (b,h)
  transpose_cvt<bf16><<<dim3(2, 32, 64), 256, 0, stream>>>(vbuf, vtb, 1024, 64);
  // attention
  attn_kernel<<<dim3(1024), 256, 0, stream>>>(qbuf, kbuf, vtb, attnb);
  // output projection, split-K=2 (partials) -> proj[0], proj[1]
  gemm256<<<128, 512, 0, stream>>>(attnb, 1024, wot, 1024, 4096, 1024, 512,
                                   16, 4, 2, wo_b,
                                   proj, nullptr, nullptr, nullptr, nullptr, EPI_F32);
  // LN1: h = LN(x + projA + projB)
  ln_kernel<<<4096, 256, 0, stream>>>(x, proj, proj + (size_t)NTOK * 1024,
                                      g1, b1, hbuf, hb);
  // FF1 + ReLU: [4096,1024] x [2048,1024]^T, 128 blocks
  gemm256<<<128, 512, 0, stream>>>(hb, 1024, ff1t, 1024, 4096, 2048, 1024,
                                   16, 8, 1, ff1b,
                                   nullptr, ff1o, nullptr, nullptr, nullptr, EPI_RELU_BF16);
  // FF2: [4096,2048] x [1024,2048]^T, split-K=2 -> proj partials (reused)
  gemm256<<<128, 512, 0, stream>>>(ff1o, 2048, ff2t, 2048, 4096, 1024, 1024,
                                   16, 4, 2, ff2b,
                                   proj, nullptr, nullptr, nullptr, nullptr, EPI_F32);
  // LN2 -> d_out
  ln_kernel<<<4096, 256, 0, stream>>>(hbuf, proj, proj + (size_t)NTOK * 1024,
                                      g2, b2, (float*)d_out, nullptr);
}

// Round 4
// 234.655 us; speedup vs baseline: 1.2468x; 1.1761x over previous
//
#include <hip/hip_runtime.h>
#include <hip/hip_bf16.h>

typedef __attribute__((ext_vector_type(8))) short bf16x8;
typedef __attribute__((ext_vector_type(4))) float f32x4;
using bf16 = __hip_bfloat16;

#define NTOK 4096
#define EPS_LN 1e-5f

enum { EPI_F32 = 0, EPI_QKV = 1, EPI_RELU_BF16 = 2 };

__device__ inline void gload_lds16(const void* g, void* l) {
  __builtin_amdgcn_global_load_lds(
      (const __attribute__((address_space(1))) char*)g,
      (__attribute__((address_space(3))) char*)l, 16, 0, 0);
}

__device__ inline unsigned ldsoff(const void* p) {
  return (unsigned)(size_t)(const __attribute__((address_space(3))) char*)p;
}

__device__ inline unsigned short f2bfu(float x) {
  bf16 h = __float2bfloat16(x);
  return __builtin_bit_cast(unsigned short, h);
}
__device__ inline bf16 to_bf16(float v) { return __float2bfloat16(v); }
__device__ inline bf16 to_bf16(bf16 v) { return v; }

// ---------------- prep kernels ----------------

__global__ __launch_bounds__(256) void cvt_bf16_kernel(const float* __restrict__ src,
                                                       bf16* __restrict__ dst, int n4) {
  int i = blockIdx.x * 256 + threadIdx.x;
  if (i >= n4) return;
  float4 v = ((const float4*)src)[i];
  ushort4 o;
  o.x = f2bfu(v.x); o.y = f2bfu(v.y); o.z = f2bfu(v.z); o.w = f2bfu(v.w);
  ((ushort4*)dst)[i] = o;
}

template <typename ST>
__global__ __launch_bounds__(256) void transpose_cvt(const ST* __restrict__ src,
                                                     bf16* __restrict__ dst, int R, int C) {
  __shared__ bf16 tile[32][33];
  int o = blockIdx.z;
  int r0 = blockIdx.y * 32, c0 = blockIdx.x * 32;
  int tx = threadIdx.x & 31, ty = threadIdx.x >> 5;
  const ST* s = src + (size_t)o * R * C;
  bf16* d = dst + (size_t)o * R * C;
#pragma unroll
  for (int i = 0; i < 32; i += 8)
    tile[ty + i][tx] = to_bf16(s[(size_t)(r0 + ty + i) * C + (c0 + tx)]);
  __syncthreads();
#pragma unroll
  for (int i = 0; i < 32; i += 8)
    d[(size_t)(c0 + ty + i) * R + (r0 + tx)] = tile[tx][ty + i];
}

__global__ __launch_bounds__(256) void pack_bias_kernel(const float* __restrict__ bq,
                                                        const float* __restrict__ bk,
                                                        const float* __restrict__ bv,
                                                        float* __restrict__ out) {
  int i = blockIdx.x * 256 + threadIdx.x;
  if (i >= 3072) return;
  out[i] = (i < 1024) ? bq[i] : (i < 2048 ? bk[i - 1024] : bv[i - 2048]);
}

// ---------------- GEMM: 256x256 tile, 8-phase pipelined, swizzled LDS ----------
// C[M,N] = A[M,K] x Bt[N,K]^T ; optional split-K partials. 512 thr = 8 waves.

#define VM4 asm volatile("s_waitcnt vmcnt(4)" ::: "memory")
#define VM0 asm volatile("s_waitcnt vmcnt(0)" ::: "memory")
#define NOVM
#define DSR(dst, ad) asm volatile("ds_read_b128 %0, %1" : "=v"(dst) : "v"(ad))

#define LA(D, MH) { _Pragma("unroll") for (int i = 0; i < 4; ++i) { \
    DSR(a[i][0], adA[i][0] + ((D) * 32768u + (MH) * 8192u)); \
    DSR(a[i][1], adA[i][1] + ((D) * 32768u + (MH) * 8192u)); } }

#define LB(D, NH, BN_) { _Pragma("unroll") for (int j = 0; j < 2; ++j) { \
    DSR(BN_[j][0], adB[j][0] + ((D) * 32768u + (NH) * 4096u)); \
    DSR(BN_[j][1], adB[j][1] + ((D) * 32768u + (NH) * 4096u)); } }

// stage pointers: 2 per-lane base ptrs; (q,h) deltas are wave-uniform imm*ld
#define SA(C, H, DD) { _Pragma("unroll") for (int q = 0; q < 2; ++q) \
    gload_lds16(gA0 + (C) + (size_t)((H) * 128 + q * 64) * lda2, \
                sAbase + (DD) * 32768 + (H) * 16384 + (q * 8 + w) * 1024); }
#define SB(C, H, DD) { _Pragma("unroll") for (int q = 0; q < 2; ++q) \
    gload_lds16(gB0 + (C) + (size_t)((H) * 128 + q * 64) * ldb2, \
                sBbase + (DD) * 32768 + (H) * 16384 + (q * 8 + w) * 1024); }

#define PHASE(MH, NH, BN_, LOADS, STAGE, VMS) { \
  LOADS; \
  STAGE; \
  __builtin_amdgcn_s_barrier(); \
  asm volatile("s_waitcnt lgkmcnt(0)" ::: "memory"); \
  __builtin_amdgcn_sched_barrier(0); \
  __builtin_amdgcn_s_setprio(1); \
  _Pragma("unroll") for (int i = 0; i < 4; ++i) \
  _Pragma("unroll") for (int j = 0; j < 2; ++j) \
  _Pragma("unroll") for (int kk = 0; kk < 2; ++kk) \
    acc[(MH) * 4 + i][(NH) * 2 + j] = __builtin_amdgcn_mfma_f32_16x16x32_bf16( \
        a[i][kk], BN_[j][kk], acc[(MH) * 4 + i][(NH) * 2 + j], 0, 0, 0); \
  __builtin_amdgcn_s_setprio(0); \
  VMS; \
  __builtin_amdgcn_s_barrier(); \
}

__global__ __launch_bounds__(512, 2) void gemm256(
    const bf16* __restrict__ A, int lda,
    const bf16* __restrict__ Bt, int ldb,
    int M, int N, int K,  // K = per-split extent
    int nbm, int nbn, int nsplit,
    const float* __restrict__ bias,
    float* __restrict__ Cf, bf16* __restrict__ Cb,
    bf16* __restrict__ Qd, bf16* __restrict__ Kd, bf16* __restrict__ Vd,
    int mode) {
  __shared__ bf16 sA[2][256][64];
  __shared__ bf16 sB[2][256][64];
  const int nwg = nbm * nbn * nsplit;
  const int orig = blockIdx.x;
  const int wgid = (orig % 8) * (nwg / 8) + orig / 8;  // nwg % 8 == 0
  const int sp = wgid / (nbm * nbn);
  const int rem = wgid % (nbm * nbn);
  const int bm = rem / nbn, bn = rem % nbn;
  const int tid = threadIdx.x;
  const int w = tid >> 6, lane = tid & 63;
  const int wm = w >> 2, wn = w & 3;
  const int ri = lane & 15, kg = lane >> 4;
  const bf16* Ab = A + (size_t)bm * 256 * lda + (size_t)sp * K;
  const bf16* Bb = Bt + (size_t)bn * 256 * ldb + (size_t)sp * K;
  const int NT = K / 64;
  const size_t lda2 = (size_t)lda * 2, ldb2 = (size_t)ldb * 2;
  char* sAbase = (char*)&sA[0][0][0];
  char* sBbase = (char*)&sB[0][0][0];

  // loop-invariant LDS read addresses
  unsigned adA[4][2], adB[2][2];
  const unsigned sA0 = ldsoff(sAbase), sB0 = ldsoff(sBbase);
#pragma unroll
  for (int i = 0; i < 4; ++i) {
    int row = wm * 128 + i * 16 + ri;
    unsigned swz = (unsigned)((row & 7) << 4);
    adA[i][0] = sA0 + row * 128 + ((kg * 16) ^ swz);
    adA[i][1] = sA0 + row * 128 + ((64 + kg * 16) ^ swz);
  }
#pragma unroll
  for (int j = 0; j < 2; ++j) {
    int row = wn * 64 + j * 16 + ri;
    unsigned swz = (unsigned)((row & 7) << 4);
    adB[j][0] = sB0 + row * 128 + ((kg * 16) ^ swz);
    adB[j][1] = sB0 + row * 128 + ((64 + kg * 16) ^ swz);
  }

  // per-lane stage base pointers (q=h=0), advanced +256B per tile-pair
  const int cb0 = ((lane & 7) * 16) ^ (((lane >> 3) & 7) << 4);
  const char* gA0 = (const char*)Ab + (size_t)(w * 8 + (lane >> 3)) * lda2 + cb0;
  const char* gB0 = (const char*)Bb + (size_t)(w * 8 + (lane >> 3)) * ldb2 + cb0;

  f32x4 acc[8][4] = {};
  bf16x8 a[4][2], bA[2][2], bB[2][2];

  // prologue: tile0 A+B, tile1 B
  SA(0, 0, 0) SA(0, 1, 0) SB(0, 0, 0) SB(0, 1, 0) SB(128, 0, 1) SB(128, 1, 1)
  VM4;
  __builtin_amdgcn_s_barrier();

  const int niter = (NT - 2) / 2;
  for (int it = 0; it < niter; ++it) {
    // tile t (dbuf 0)
    PHASE(0, 0, bA, LA(0, 0); LB(0, 0, bA), SA(128, 0, 1), NOVM)
    PHASE(0, 1, bB, LB(0, 1, bB),           SA(128, 1, 1), NOVM)
    PHASE(1, 0, bA, LA(0, 1),               SB(256, 0, 0), NOVM)
    PHASE(1, 1, bB, ,                       SB(256, 1, 0), VM4)
    // tile t+1 (dbuf 1)
    PHASE(0, 0, bA, LA(1, 0); LB(1, 0, bA), SA(256, 0, 0), NOVM)
    PHASE(0, 1, bB, LB(1, 1, bB),           SA(256, 1, 0), NOVM)
    PHASE(1, 0, bA, LA(1, 1),               SB(384, 0, 1), NOVM)
    PHASE(1, 1, bB, ,                       SB(384, 1, 1), VM4)
    gA0 += 256; gB0 += 256;
  }
  // tail: tiles NT-2 (dbuf0), NT-1 (dbuf1); stage only A(NT-1)
  PHASE(0, 0, bA, LA(0, 0); LB(0, 0, bA), SA(128, 0, 1), NOVM)
  PHASE(0, 1, bB, LB(0, 1, bB),           SA(128, 1, 1), NOVM)
  PHASE(1, 0, bA, LA(0, 1),               ,              NOVM)
  PHASE(1, 1, bB, ,                       ,              VM0)
  PHASE(0, 0, bA, LA(1, 0); LB(1, 0, bA), ,              NOVM)
  PHASE(0, 1, bB, LB(1, 1, bB),           ,              NOVM)
  PHASE(1, 0, bA, LA(1, 1),               ,              NOVM)
  PHASE(1, 1, bB, ,                       ,              NOVM)

  // epilogue: line-contiguous writes (nf innermost)
  const int colbase = bn * 256 + wn * 64 + ri;
  float bv4[4];
#pragma unroll
  for (int nf = 0; nf < 4; ++nf)
    bv4[nf] = (bias && sp == 0) ? bias[colbase + nf * 16] : 0.f;

  if (mode == EPI_QKV) {
    int col0 = bn * 256 + wn * 64;  // which/hh are wave-uniform (256 | 1024 grid)
    int which = col0 >> 10, hh = (col0 >> 6) & 15;
    bf16* dst = (which == 0) ? Qd : (which == 1) ? Kd : Vd;
#pragma unroll
    for (int mf = 0; mf < 8; ++mf)
#pragma unroll
      for (int r = 0; r < 4; ++r) {
        int row = bm * 256 + wm * 128 + mf * 16 + kg * 4 + r;
        int b = row >> 10, s = row & 1023;
        bf16* o = dst + (((size_t)(b * 16 + hh)) * 1024 + s) * 64;
#pragma unroll
        for (int nf = 0; nf < 4; ++nf)
          o[nf * 16 + ri] = __float2bfloat16(acc[mf][nf][r] + bv4[nf]);
      }
  } else if (mode == EPI_F32) {
#pragma unroll
    for (int mf = 0; mf < 8; ++mf)
#pragma unroll
      for (int r = 0; r < 4; ++r) {
        int row = bm * 256 + wm * 128 + mf * 16 + kg * 4 + r;
        float* o = Cf + (size_t)sp * M * N + (size_t)row * N + colbase;
#pragma unroll
        for (int nf = 0; nf < 4; ++nf) o[nf * 16] = acc[mf][nf][r] + bv4[nf];
      }
  } else {  // EPI_RELU_BF16
#pragma unroll
    for (int mf = 0; mf < 8; ++mf)
#pragma unroll
      for (int r = 0; r < 4; ++r) {
        int row = bm * 256 + wm * 128 + mf * 16 + kg * 4 + r;
        bf16* o = Cb + (size_t)row * N + colbase;
#pragma unroll
        for (int nf = 0; nf < 4; ++nf) {
          float v = acc[mf][nf][r] + bv4[nf];
          o[nf * 16] = __float2bfloat16(v > 0.f ? v : 0.f);
        }
      }
  }
}

// ---------------- flash attention: T2-swizzled Ks/Vt/Ps ----------------
// grid: 64 (b,h) * 16 q-tiles ; block 256 = 4 waves, each wave 16 q-rows.
__global__ __launch_bounds__(256) void attn_kernel(
    const bf16* __restrict__ Qb, const bf16* __restrict__ Kb,
    const bf16* __restrict__ VTb, bf16* __restrict__ Ob) {
  __shared__ bf16 Ks[64][64];
  __shared__ bf16 Vt[64][64];     // [d][key]
  __shared__ bf16 Ps[4][16][64];  // per-wave P buffer
  int bh = blockIdx.x >> 4;
  int qt = blockIdx.x & 15;
  int bb = bh >> 4, hh = bh & 15;
  int tid = threadIdx.x, wid = tid >> 6, lane = tid & 63;
  int ri = lane & 15, kg = lane >> 4;
  int r8 = lane >> 3;
  const int cb = ((lane & 7) * 16) ^ ((r8 & 7) << 4);  // pre-swizzled source
  const unsigned rsw = (unsigned)((ri & 7) << 4);
  const bf16* qp = Qb + (size_t)bh * 1024 * 64;
  const bf16* kp = Kb + (size_t)bh * 1024 * 64;
  const bf16* vp = VTb + (size_t)bh * 64 * 1024;
  int q0 = qt * 64 + wid * 16;

  bf16x8 qf[2];
  qf[0] = *(const bf16x8*)(qp + (size_t)(q0 + ri) * 64 + kg * 8);
  qf[1] = *(const bf16x8*)(qp + (size_t)(q0 + ri) * 64 + 32 + kg * 8);

  f32x4 oacc[4] = {};
  float mrun[4] = {-1e30f, -1e30f, -1e30f, -1e30f};
  float lrun[4] = {0.f, 0.f, 0.f, 0.f};
  char* pb = (char*)Ps + wid * 2048;

  for (int t = 0; t < 16; ++t) {
    int k0 = t * 64;
#pragma unroll
    for (int c = 0; c < 2; ++c) {
      int chunk = wid * 2 + c;
      gload_lds16((const char*)(kp + (size_t)(k0 + chunk * 8 + r8) * 64) + cb,
                  (char*)Ks + chunk * 1024);
      gload_lds16((const char*)(vp + (size_t)(chunk * 8 + r8) * 1024 + k0) + cb,
                  (char*)Vt + chunk * 1024);
    }
    __syncthreads();

    f32x4 sac[4] = {};
#pragma unroll
    for (int kk = 0; kk < 2; ++kk) {
      unsigned ko = (unsigned)(kk * 64 + kg * 16);
#pragma unroll
      for (int n = 0; n < 4; ++n) {
        bf16x8 kf = *(const bf16x8*)((const char*)Ks + (n * 16 + ri) * 128 + (ko ^ rsw));
        sac[n] = __builtin_amdgcn_mfma_f32_16x16x32_bf16(qf[kk], kf, sac[n], 0, 0, 0);
      }
    }
    // online softmax (rows = kg*4+r, cols = n*16 + ri)
#pragma unroll
    for (int r = 0; r < 4; ++r) {
      float s0 = sac[0][r] * 0.125f, s1 = sac[1][r] * 0.125f;
      float s2 = sac[2][r] * 0.125f, s3 = sac[3][r] * 0.125f;
      float mt = fmaxf(fmaxf(s0, s1), fmaxf(s2, s3));
      mt = fmaxf(mt, __shfl_xor(mt, 1));
      mt = fmaxf(mt, __shfl_xor(mt, 2));
      mt = fmaxf(mt, __shfl_xor(mt, 4));
      mt = fmaxf(mt, __shfl_xor(mt, 8));
      float mnew = fmaxf(mrun[r], mt);
      float corr = __expf(mrun[r] - mnew);
      mrun[r] = mnew;
      lrun[r] *= corr;
      oacc[0][r] *= corr; oacc[1][r] *= corr; oacc[2][r] *= corr; oacc[3][r] *= corr;
      float p0 = __expf(s0 - mnew), p1 = __expf(s1 - mnew);
      float p2 = __expf(s2 - mnew), p3 = __expf(s3 - mnew);
      float ps = p0 + p1 + p2 + p3;
      ps += __shfl_xor(ps, 1); ps += __shfl_xor(ps, 2);
      ps += __shfl_xor(ps, 4); ps += __shfl_xor(ps, 8);
      lrun[r] += ps;
      int prow = kg * 4 + r;
      unsigned psw = (unsigned)((prow & 7) << 4);
      char* pr = pb + prow * 128;
      *(bf16*)(pr + ((ri * 2) ^ psw)) = __float2bfloat16(p0);
      *(bf16*)(pr + ((32 + ri * 2) ^ psw)) = __float2bfloat16(p1);
      *(bf16*)(pr + ((64 + ri * 2) ^ psw)) = __float2bfloat16(p2);
      *(bf16*)(pr + ((96 + ri * 2) ^ psw)) = __float2bfloat16(p3);
    }
    // PV: O += P[16,64] x Vt
#pragma unroll
    for (int kk = 0; kk < 2; ++kk) {
      unsigned ko = (unsigned)(kk * 64 + kg * 16);
      bf16x8 pf = *(const bf16x8*)(pb + ri * 128 + (ko ^ rsw));
#pragma unroll
      for (int n = 0; n < 4; ++n) {
        bf16x8 vf = *(const bf16x8*)((const char*)Vt + (n * 16 + ri) * 128 + (ko ^ rsw));
        oacc[n] = __builtin_amdgcn_mfma_f32_16x16x32_bf16(pf, vf, oacc[n], 0, 0, 0);
      }
    }
    __syncthreads();
  }

#pragma unroll
  for (int r = 0; r < 4; ++r) {
    float inv = 1.f / lrun[r];
    int s = q0 + kg * 4 + r;
    size_t base = ((size_t)(bb * 1024 + s)) * 1024 + hh * 64;
#pragma unroll
    for (int n = 0; n < 4; ++n)
      Ob[base + n * 16 + ri] = __float2bfloat16(oacc[n][r] * inv);
  }
}

// ---------------- fused residual + LayerNorm (2 or 3 inputs) ----------------
__global__ __launch_bounds__(256) void ln_kernel(
    const float* __restrict__ a, const float* __restrict__ b,
    const float* __restrict__ c,
    const float* __restrict__ gamma, const float* __restrict__ beta,
    float* __restrict__ out_f32, bf16* __restrict__ out_bf16) {
  int row = blockIdx.x;
  int tid = threadIdx.x;
  float4 av = ((const float4*)(a + (size_t)row * 1024))[tid];
  float4 bv = ((const float4*)(b + (size_t)row * 1024))[tid];
  float4 z;
  z.x = av.x + bv.x; z.y = av.y + bv.y; z.z = av.z + bv.z; z.w = av.w + bv.w;
  if (c) {
    float4 cv = ((const float4*)(c + (size_t)row * 1024))[tid];
    z.x += cv.x; z.y += cv.y; z.z += cv.z; z.w += cv.w;
  }
  float s = z.x + z.y + z.z + z.w;
  float ss = z.x * z.x + z.y * z.y + z.z * z.z + z.w * z.w;
#pragma unroll
  for (int o = 32; o >= 1; o >>= 1) { s += __shfl_xor(s, o); ss += __shfl_xor(ss, o); }
  __shared__ float red[8];
  int wid = tid >> 6;
  if ((tid & 63) == 0) { red[wid] = s; red[4 + wid] = ss; }
  __syncthreads();
  s = red[0] + red[1] + red[2] + red[3];
  ss = red[4] + red[5] + red[6] + red[7];
  float mean = s * (1.f / 1024.f);
  float var = ss * (1.f / 1024.f) - mean * mean;
  var = var > 0.f ? var : 0.f;
  float inv = 1.f / (sqrtf(var) + EPS_LN);
  float4 g = ((const float4*)gamma)[tid];
  float4 be = ((const float4*)beta)[tid];
  float4 y;
  y.x = (z.x - mean) * inv * g.x + be.x;
  y.y = (z.y - mean) * inv * g.y + be.y;
  y.z = (z.z - mean) * inv * g.z + be.z;
  y.w = (z.w - mean) * inv * g.w + be.w;
  ((float4*)(out_f32 + (size_t)row * 1024))[tid] = y;
  if (out_bf16) {
    ushort4 o;
    o.x = f2bfu(y.x); o.y = f2bfu(y.y); o.z = f2bfu(y.z); o.w = f2bfu(y.w);
    ((ushort4*)(out_bf16 + (size_t)row * 1024))[tid] = o;
  }
}

// ---------------- launch ----------------
extern "C" void kernel_launch(void* const* d_in, const int* in_sizes, int n_in,
                              void* d_out, int out_size, void* d_ws, size_t ws_size,
                              hipStream_t stream) {
  const float* x = (const float*)d_in[0];
  const float* wq = (const float*)d_in[1];
  const float* bq = (const float*)d_in[2];
  const float* wk = (const float*)d_in[3];
  const float* bk = (const float*)d_in[4];
  const float* wv = (const float*)d_in[5];
  const float* bv = (const float*)d_in[6];
  const float* wo_w = (const float*)d_in[7];
  const float* wo_b = (const float*)d_in[8];
  const float* g1 = (const float*)d_in[9];
  const float* b1 = (const float*)d_in[10];
  const float* ff1w = (const float*)d_in[11];
  const float* ff1b = (const float*)d_in[12];
  const float* ff2w = (const float*)d_in[13];
  const float* ff2b = (const float*)d_in[14];
  const float* g2 = (const float*)d_in[15];
  const float* b2 = (const float*)d_in[16];

  char* ws = (char*)d_ws;
  size_t off = 0;
  auto alloc = [&](size_t bytes) {
    char* p = ws + off;
    off += (bytes + 255) & ~(size_t)255;
    return p;
  };
  bf16* xb = (bf16*)alloc((size_t)NTOK * 1024 * 2);
  bf16* wqkvt = (bf16*)alloc((size_t)3072 * 1024 * 2);
  bf16* wot = (bf16*)alloc((size_t)1024 * 1024 * 2);
  bf16* ff1t = (bf16*)alloc((size_t)2048 * 1024 * 2);
  bf16* ff2t = (bf16*)alloc((size_t)1024 * 2048 * 2);
  float* qkvbias = (float*)alloc(3072 * 4);
  bf16* qbuf = (bf16*)alloc((size_t)64 * 1024 * 64 * 2);
  bf16* kbuf = (bf16*)alloc((size_t)64 * 1024 * 64 * 2);
  bf16* vbuf = (bf16*)alloc((size_t)64 * 1024 * 64 * 2);
  bf16* vtb = (bf16*)alloc((size_t)64 * 64 * 1024 * 2);
  bf16* attnb = (bf16*)alloc((size_t)NTOK * 1024 * 2);
  float* proj = (float*)alloc((size_t)2 * NTOK * 1024 * 4);  // 2 split-K partials
  bf16* hb = (bf16*)alloc((size_t)NTOK * 1024 * 2);
  bf16* ff1o = qbuf;            // reuse q+k region (dead after attention)
  float* hbuf = (float*)d_out;  // f32 h scratch (fully rewritten by LN2)

  // prep
  cvt_bf16_kernel<<<(NTOK * 1024 / 4 + 255) / 256, 256, 0, stream>>>(x, xb, NTOK * 1024 / 4);
  transpose_cvt<float><<<dim3(2, 32, 16), 256, 0, stream>>>(wq, wqkvt, 1024, 64);
  transpose_cvt<float><<<dim3(2, 32, 16), 256, 0, stream>>>(wk, wqkvt + 1024 * 1024, 1024, 64);
  transpose_cvt<float><<<dim3(2, 32, 16), 256, 0, stream>>>(wv, wqkvt + 2 * 1024 * 1024, 1024, 64);
  transpose_cvt<float><<<dim3(32, 32, 1), 256, 0, stream>>>(wo_w, wot, 1024, 1024);
  transpose_cvt<float><<<dim3(64, 32, 1), 256, 0, stream>>>(ff1w, ff1t, 1024, 2048);
  transpose_cvt<float><<<dim3(32, 64, 1), 256, 0, stream>>>(ff2w, ff2t, 2048, 1024);
  pack_bias_kernel<<<12, 256, 0, stream>>>(bq, bk, bv, qkvbias);

  // QKV: [4096,1024] x [3072,1024]^T, 192 blocks
  gemm256<<<192, 512, 0, stream>>>(xb, 1024, wqkvt, 1024, 4096, 3072, 1024,
                                   16, 12, 1, qkvbias,
                                   nullptr, nullptr, qbuf, kbuf, vbuf, EPI_QKV);
  // V -> V^T per (b,h)
  transpose_cvt<bf16><<<dim3(2, 32, 64), 256, 0, stream>>>(vbuf, vtb, 1024, 64);
  // attention
  attn_kernel<<<dim3(1024), 256, 0, stream>>>(qbuf, kbuf, vtb, attnb);
  // output projection, split-K=2 (partials) -> proj[0], proj[1]
  gemm256<<<128, 512, 0, stream>>>(attnb, 1024, wot, 1024, 4096, 1024, 512,
                                   16, 4, 2, wo_b,
                                   proj, nullptr, nullptr, nullptr, nullptr, EPI_F32);
  // LN1: h = LN(x + projA + projB)
  ln_kernel<<<4096, 256, 0, stream>>>(x, proj, proj + (size_t)NTOK * 1024,
                                      g1, b1, hbuf, hb);
  // FF1 + ReLU: [4096,1024] x [2048,1024]^T, 128 blocks
  gemm256<<<128, 512, 0, stream>>>(hb, 1024, ff1t, 1024, 4096, 2048, 1024,
                                   16, 8, 1, ff1b,
                                   nullptr, ff1o, nullptr, nullptr, nullptr, EPI_RELU_BF16);
  // FF2: [4096,2048] x [1024,2048]^T, split-K=2 -> proj partials (reused)
  gemm256<<<128, 512, 0, stream>>>(ff1o, 2048, ff2t, 2048, 4096, 1024, 1024,
                                   16, 4, 2, ff2b,
                                   proj, nullptr, nullptr, nullptr, nullptr, EPI_F32);
  // LN2 -> d_out
  ln_kernel<<<4096, 256, 0, stream>>>(hbuf, proj, proj + (size_t)NTOK * 1024,
                                      g2, b2, (float*)d_out, nullptr);
}